// Round 2
// baseline (791.041 us; speedup 1.0000x reference)
//
#include <hip/hip_runtime.h>
#include <hip/hip_bf16.h>
#include <math.h>

typedef unsigned short u16;
typedef __attribute__((ext_vector_type(8))) short bf16x8;
typedef __attribute__((ext_vector_type(4))) float f32x4;
typedef __attribute__((ext_vector_type(4))) int i32x4;

#define PV 10

__device__ __forceinline__ float bf2f(u16 u){
  union{unsigned int i; float f;} v; v.i = ((unsigned int)u)<<16; return v.f;
}
__device__ __forceinline__ u16 f2bf(float f){
  union{float f; unsigned int i;} v; v.f = f;
  unsigned int r = (v.i + 0x7FFFu + ((v.i>>16)&1u))>>16;
  return (u16)r;
}
__device__ __forceinline__ float eluf(float z){
  return z > 0.f ? z : expm1f(z);
}
// flexible-dtype param load: f32 flag ? float : bf16
__device__ __forceinline__ float ldp(const void* p, int i, int f32f){
  return f32f ? ((const float*)p)[i] : bf2f(((const u16*)p)[i]);
}
// LDS byte-offset swizzle: rows stride 512B; XOR bits 4-6.
__device__ __forceinline__ int swz(int row, int cb){
  int m = ((row & 7) << 4) ^ ((row & 8) << 2);
  return (row << 9) + (cb ^ m);
}

// ---------------- dtype sniff: decide if inputs are f32 or bf16 ----------------
// Under bf16, x's even u16s are N(0,1) bf16 values (exponent 113..132 w.p. ~1).
// Under f32, even u16s are low mantissa halves (uniform exponent, ~9% in range).
__global__ void k_sniff(const u16* __restrict__ x, int* __restrict__ flag){
  int t = threadIdx.x;
  u16 u = x[2*t];
  int e = (u >> 7) & 0xFF;
  int sane = (e >= 113 && e <= 134) ? 1 : 0;
  unsigned long long b = __ballot(sane);
  if (t == 0) *flag = (__popcll(b) < 32) ? 1 : 0;   // 1 = f32 inputs
}

// ---------------- weight transpose+canonicalize: W[k][n] -> WT[n][k] bf16 ----------------
__global__ void k_transpose(const int* __restrict__ flagp,
                            const void* __restrict__ W1, const void* __restrict__ W2,
                            const void* __restrict__ Wa, const void* __restrict__ Wo,
                            u16* __restrict__ W1T, u16* __restrict__ W2T,
                            u16* __restrict__ WaT, u16* __restrict__ WoT)
{
  const int f = *flagp;
  int idx = blockIdx.x * 256 + threadIdx.x;
  if (idx < 65536) {                       // W_in2hid 256x256
    int n = idx >> 8, k = idx & 255;
    W1T[idx] = f2bf(ldp(W1, k*256 + n, f));
  } else if (idx < 131072) {               // W_enc 256x256
    int j = idx - 65536;
    int n = j >> 8, k = j & 255;
    W2T[j] = f2bf(ldp(W2, k*256 + n, f));
  } else if (idx < 262144) {               // W_aggr 512x256 -> 256x512
    int j = idx - 131072;
    int n = j >> 9, k = j & 511;
    WaT[n*512 + k] = f2bf(ldp(Wa, k*256 + n, f));
  } else {                                 // W_out 256x64 -> 64x256
    int j = idx - 262144;
    int n = j >> 8, k = j & 255;
    WoT[n*256 + k] = f2bf(ldp(Wo, k*64 + n, f));
  }
}

// ---------------- virtual nodes: layers 1-2 for P rows, fold W_aggr bottom + b_aggr into vg ----------------
__global__ void k_vnode(const int* __restrict__ flagp,
                        const void* __restrict__ embed, const u16* __restrict__ W1T,
                        const void* __restrict__ b1, const void* __restrict__ g1, const void* __restrict__ bb1,
                        const void* __restrict__ vbh,
                        const u16* __restrict__ W2T, const void* __restrict__ b2,
                        const void* __restrict__ vbd,
                        const u16* __restrict__ WaT, const void* __restrict__ ba,
                        float* __restrict__ vg)
{
  __shared__ float buf[PV][256];
  __shared__ float st[PV][2];
  const int f = *flagp;
  int t = threadIdx.x;

  for (int r=0;r<PV;r++) buf[r][t] = ldp(embed, r*256 + t, f);
  __syncthreads();

  float z[PV];
  for (int r=0;r<PV;r++){
    float s = ldp(b1, t, f);
    for (int k8=0;k8<32;k8++){
      bf16x8 w = *(const bf16x8*)(W1T + t*256 + k8*8);
      #pragma unroll
      for (int j=0;j<8;j++) s += buf[r][k8*8+j] * bf2f((u16)w[j]);
    }
    z[r] = s;
  }
  __syncthreads();
  for (int r=0;r<PV;r++) buf[r][t] = z[r];
  __syncthreads();
  if (t < PV){
    float s=0.f, ss=0.f;
    for (int c=0;c<256;c++){ float v = buf[t][c]; s+=v; ss+=v*v; }
    float mu = s*(1.f/256.f);
    float var = ss*(1.f/256.f) - mu*mu;
    st[t][0] = mu; st[t][1] = rsqrtf(var + 1e-5f);
  }
  __syncthreads();
  for (int r=0;r<PV;r++){
    float v = (z[r] - st[r][0]) * st[r][1] * ldp(g1, t, f) + ldp(bb1, t, f);
    buf[r][t] = eluf(v) + ldp(vbh, r*256 + t, f);
  }
  __syncthreads();
  for (int r=0;r<PV;r++){
    float s = ldp(b2, t, f);
    for (int k8=0;k8<32;k8++){
      bf16x8 w = *(const bf16x8*)(W2T + t*256 + k8*8);
      #pragma unroll
      for (int j=0;j<8;j++) s += buf[r][k8*8+j] * bf2f((u16)w[j]);
    }
    z[r] = eluf(s) + ldp(vbd, r*256 + t, f);
  }
  __syncthreads();
  for (int r=0;r<PV;r++) buf[r][t] = z[r];
  __syncthreads();
  for (int r=0;r<PV;r++){
    float s = ldp(ba, t, f);
    for (int k8=0;k8<32;k8++){
      bf16x8 w = *(const bf16x8*)(WaT + t*512 + 256 + k8*8);
      #pragma unroll
      for (int j=0;j<8;j++) s += buf[r][k8*8+j] * bf2f((u16)w[j]);
    }
    vg[r*256 + t] = s;
  }
}

// ---------------- cross-wave LayerNorm stats ----------------
__device__ __forceinline__ void ln_rows(f32x4 (&acc)[4][4], float2 (*part)[4], float2* stats,
                                        int tid, int wid, int q, int g)
{
  #pragma unroll
  for (int m=0;m<4;m++){
    #pragma unroll
    for (int j=0;j<4;j++){
      float s1=0.f, s2=0.f;
      #pragma unroll
      for (int n=0;n<4;n++){ float v = acc[m][n][j]; s1+=v; s2+=v*v; }
      s1 += __shfl_xor(s1,1,64); s2 += __shfl_xor(s2,1,64);
      s1 += __shfl_xor(s1,2,64); s2 += __shfl_xor(s2,2,64);
      s1 += __shfl_xor(s1,4,64); s2 += __shfl_xor(s2,4,64);
      s1 += __shfl_xor(s1,8,64); s2 += __shfl_xor(s2,8,64);
      if (q == 0) part[16*m + 4*g + j][wid] = make_float2(s1, s2);
    }
  }
  __syncthreads();
  if (tid < 64){
    float s=0.f, ss=0.f;
    #pragma unroll
    for (int w=0;w<4;w++){ float2 p = part[tid][w]; s+=p.x; ss+=p.y; }
    float mu = s*(1.f/256.f);
    float var = ss*(1.f/256.f) - mu*mu;
    stats[tid] = make_float2(mu, rsqrtf(var + 1e-5f));
  }
  __syncthreads();
}

// ---------------- main fused kernel ----------------
__global__ __launch_bounds__(256, 2) void k_main(
    const int* __restrict__ flagp,
    const void* __restrict__ x, const int* __restrict__ mapping,
    const void* __restrict__ b1, const void* __restrict__ g1, const void* __restrict__ bb1,
    const void* __restrict__ b2,
    const void* __restrict__ g3, const void* __restrict__ bb3,
    const void* __restrict__ bo,
    const u16* __restrict__ W1T, const u16* __restrict__ W2T,
    const u16* __restrict__ WaT, const u16* __restrict__ WoT,
    const float* __restrict__ vg, void* __restrict__ out)
{
  __shared__ __align__(16) u16 Abuf[64*256];
  __shared__ float2 part[64][4];
  __shared__ float2 stats[64];
  __shared__ int maplds[64];

  const int f = *flagp;
  const int tid = threadIdx.x;
  const int wid = tid >> 6;
  const int lane = tid & 63;
  const int q = lane & 15;
  const int g = lane >> 4;
  const int R0 = blockIdx.x * 64;

  // ---- stage x tile (64 x 256) into swizzled LDS as bf16 ----
  if (f) {
    const float* xr = (const float*)x + (size_t)R0 * 256;
    #pragma unroll
    for (int i=0;i<8;i++){
      int c = tid + 256*i;
      int row = c >> 5;
      int cb  = (c & 31) << 4;
      int e0  = (c & 31) << 3;
      float4 a = *(const float4*)(xr + row*256 + e0);
      float4 b = *(const float4*)(xr + row*256 + e0 + 4);
      union { u16 h[8]; i32x4 v; } pk;
      pk.h[0]=f2bf(a.x); pk.h[1]=f2bf(a.y); pk.h[2]=f2bf(a.z); pk.h[3]=f2bf(a.w);
      pk.h[4]=f2bf(b.x); pk.h[5]=f2bf(b.y); pk.h[6]=f2bf(b.z); pk.h[7]=f2bf(b.w);
      *(i32x4*)((char*)Abuf + swz(row, cb)) = pk.v;
    }
  } else {
    const u16* xr = (const u16*)x + (size_t)R0 * 256;
    #pragma unroll
    for (int i=0;i<8;i++){
      int c = tid + 256*i;
      int row = c >> 5;
      int cb  = (c & 31) << 4;
      i32x4 v = *(const i32x4*)(xr + row*256 + ((c&31)<<3));
      *(i32x4*)((char*)Abuf + swz(row, cb)) = v;
    }
  }
  if (tid < 64){
    int mv = mapping[R0 + tid];
    maplds[tid] = mv < 0 ? 0 : (mv > PV-1 ? PV-1 : mv);
  }
  __syncthreads();

  f32x4 acc[4][4];

  // ================= GEMM1: h1 = elu(LN(x @ W1 + b1)) =================
  {
    #pragma unroll
    for (int n=0;n<4;n++){
      float bv = ldp(b1, 64*wid + 16*n + q, f);
      #pragma unroll
      for (int m=0;m<4;m++) acc[m][n] = (f32x4){bv,bv,bv,bv};
    }
    #pragma unroll
    for (int s=0;s<8;s++){
      bf16x8 af[4], bw[4];
      #pragma unroll
      for (int m=0;m<4;m++) af[m] = *(const bf16x8*)((const char*)Abuf + swz(16*m+q, 64*s+16*g));
      #pragma unroll
      for (int n=0;n<4;n++) bw[n] = *(const bf16x8*)(W1T + (64*wid+16*n+q)*256 + 32*s + 8*g);
      #pragma unroll
      for (int m=0;m<4;m++){
        #pragma unroll
        for (int n=0;n<4;n++)
          acc[m][n] = __builtin_amdgcn_mfma_f32_16x16x32_bf16(af[m], bw[n], acc[m][n], 0,0,0);
      }
    }
  }
  ln_rows(acc, part, stats, tid, wid, q, g);
  {
    float gam[4], bet[4];
    #pragma unroll
    for (int n=0;n<4;n++){ int col = 64*wid+16*n+q; gam[n]=ldp(g1,col,f); bet[n]=ldp(bb1,col,f); }
    #pragma unroll
    for (int m=0;m<4;m++){
      #pragma unroll
      for (int j=0;j<4;j++){
        int row = 16*m + 4*g + j;
        float2 st = stats[row];
        #pragma unroll
        for (int n=0;n<4;n++){
          float v = (acc[m][n][j] - st.x) * st.y * gam[n] + bet[n];
          *(u16*)((char*)Abuf + swz(row, (64*wid+16*n+q)<<1)) = f2bf(eluf(v));
        }
      }
    }
  }
  __syncthreads();

  // ================= GEMM2: h2 = elu(h1 @ W2 + b2) =================
  {
    #pragma unroll
    for (int n=0;n<4;n++){
      float bv = ldp(b2, 64*wid + 16*n + q, f);
      #pragma unroll
      for (int m=0;m<4;m++) acc[m][n] = (f32x4){bv,bv,bv,bv};
    }
    #pragma unroll
    for (int s=0;s<8;s++){
      bf16x8 af[4], bw[4];
      #pragma unroll
      for (int m=0;m<4;m++) af[m] = *(const bf16x8*)((const char*)Abuf + swz(16*m+q, 64*s+16*g));
      #pragma unroll
      for (int n=0;n<4;n++) bw[n] = *(const bf16x8*)(W2T + (64*wid+16*n+q)*256 + 32*s + 8*g);
      #pragma unroll
      for (int m=0;m<4;m++){
        #pragma unroll
        for (int n=0;n<4;n++)
          acc[m][n] = __builtin_amdgcn_mfma_f32_16x16x32_bf16(af[m], bw[n], acc[m][n], 0,0,0);
      }
    }
  }
  __syncthreads();
  {
    #pragma unroll
    for (int m=0;m<4;m++){
      #pragma unroll
      for (int j=0;j<4;j++){
        int row = 16*m + 4*g + j;
        #pragma unroll
        for (int n=0;n<4;n++)
          *(u16*)((char*)Abuf + swz(row, (64*wid+16*n+q)<<1)) = f2bf(eluf(acc[m][n][j]));
      }
    }
  }
  __syncthreads();

  // ================= GEMM3: nx = elu(LN(h2 @ Wa_top + vg[map])) =================
  {
    #pragma unroll
    for (int m=0;m<4;m++){
      int mp[4];
      #pragma unroll
      for (int j=0;j<4;j++) mp[j] = maplds[16*m + 4*g + j];
      #pragma unroll
      for (int n=0;n<4;n++){
        int col = 64*wid + 16*n + q;
        #pragma unroll
        for (int j=0;j<4;j++) acc[m][n][j] = vg[mp[j]*256 + col];
      }
    }
    #pragma unroll
    for (int s=0;s<8;s++){
      bf16x8 af[4], bw[4];
      #pragma unroll
      for (int m=0;m<4;m++) af[m] = *(const bf16x8*)((const char*)Abuf + swz(16*m+q, 64*s+16*g));
      #pragma unroll
      for (int n=0;n<4;n++) bw[n] = *(const bf16x8*)(WaT + (64*wid+16*n+q)*512 + 32*s + 8*g);
      #pragma unroll
      for (int m=0;m<4;m++){
        #pragma unroll
        for (int n=0;n<4;n++)
          acc[m][n] = __builtin_amdgcn_mfma_f32_16x16x32_bf16(af[m], bw[n], acc[m][n], 0,0,0);
      }
    }
  }
  ln_rows(acc, part, stats, tid, wid, q, g);
  {
    float gam[4], bet[4];
    #pragma unroll
    for (int n=0;n<4;n++){ int col = 64*wid+16*n+q; gam[n]=ldp(g3,col,f); bet[n]=ldp(bb3,col,f); }
    #pragma unroll
    for (int m=0;m<4;m++){
      #pragma unroll
      for (int j=0;j<4;j++){
        int row = 16*m + 4*g + j;
        float2 st = stats[row];
        #pragma unroll
        for (int n=0;n<4;n++){
          float v = (acc[m][n][j] - st.x) * st.y * gam[n] + bet[n];
          *(u16*)((char*)Abuf + swz(row, (64*wid+16*n+q)<<1)) = f2bf(eluf(v));
        }
      }
    }
  }
  __syncthreads();

  // ================= GEMM4: out = nx @ Wout + bo =================
  {
    f32x4 a4[4];
    #pragma unroll
    for (int n=0;n<4;n++){ float bv = ldp(bo, 16*n+q, f); a4[n] = (f32x4){bv,bv,bv,bv}; }
    #pragma unroll
    for (int s=0;s<8;s++){
      bf16x8 af = *(const bf16x8*)((const char*)Abuf + swz(16*wid+q, 64*s+16*g));
      #pragma unroll
      for (int n=0;n<4;n++){
        bf16x8 bw = *(const bf16x8*)(WoT + (16*n+q)*256 + 32*s + 8*g);
        a4[n] = __builtin_amdgcn_mfma_f32_16x16x32_bf16(af, bw, a4[n], 0,0,0);
      }
    }
    if (f){
      float* outf = (float*)out;
      #pragma unroll
      for (int n=0;n<4;n++){
        #pragma unroll
        for (int j=0;j<4;j++){
          int grow = R0 + 16*wid + 4*g + j;
          outf[(size_t)grow*64 + 16*n + q] = a4[n][j];
        }
      }
    } else {
      u16* outh = (u16*)out;
      #pragma unroll
      for (int n=0;n<4;n++){
        #pragma unroll
        for (int j=0;j<4;j++){
          int grow = R0 + 16*wid + 4*g + j;
          outh[(size_t)grow*64 + 16*n + q] = f2bf(a4[n][j]);
        }
      }
    }
  }
}

extern "C" void kernel_launch(void* const* d_in, const int* in_sizes, int n_in,
                              void* d_out, int out_size, void* d_ws, size_t ws_size,
                              hipStream_t stream)
{
  const void* x    = d_in[0];
  const int* mapping = (const int*)d_in[1];
  const void* embed= d_in[2];
  const void* vbh  = d_in[3];
  const void* vbd  = d_in[4];
  const void* W1   = d_in[5];
  const void* b1   = d_in[6];
  const void* g1   = d_in[7];
  const void* bb1  = d_in[8];
  const void* W2   = d_in[9];
  const void* b2   = d_in[10];
  const void* g3   = d_in[11];
  const void* bb3  = d_in[12];
  const void* Wa   = d_in[13];
  const void* ba   = d_in[14];
  const void* Wo   = d_in[15];
  const void* bo   = d_in[16];

  char* ws = (char*)d_ws;
  int* flagp = (int*)ws;
  u16* W1T = (u16*)(ws + 64);
  u16* W2T = (u16*)(ws + 131136);
  u16* WaT = (u16*)(ws + 262208);
  u16* WoT = (u16*)(ws + 524352);
  float* vg = (float*)(ws + 557120);

  const int N = in_sizes[1];           // 200000, divisible by 64

  k_sniff<<<1, 64, 0, stream>>>((const u16*)x, flagp);
  k_transpose<<<1088, 256, 0, stream>>>(flagp, W1, W2, Wa, Wo, W1T, W2T, WaT, WoT);
  k_vnode<<<1, 256, 0, stream>>>(flagp, embed, W1T, b1, g1, bb1, vbh, W2T, b2, vbd, WaT, ba, vg);
  k_main<<<N/64, 256, 0, stream>>>(flagp, x, mapping, b1, g1, bb1, b2, g3, bb3, bo,
                                   W1T, W2T, WaT, WoT, vg, (void*)d_out);
}

// Round 3
// 328.324 us; speedup vs baseline: 2.4093x; 2.4093x over previous
//
#include <hip/hip_runtime.h>
#include <hip/hip_bf16.h>
#include <math.h>

typedef unsigned short u16;
typedef __attribute__((ext_vector_type(8))) short bf16x8;
typedef __attribute__((ext_vector_type(4))) float f32x4;
typedef __attribute__((ext_vector_type(4))) int i32x4;

#define PV 10

__device__ __forceinline__ float bf2f(u16 u){
  union{unsigned int i; float f;} v; v.i = ((unsigned int)u)<<16; return v.f;
}
__device__ __forceinline__ u16 f2bf(float f){
  union{float f; unsigned int i;} v; v.f = f;
  unsigned int r = (v.i + 0x7FFFu + ((v.i>>16)&1u))>>16;
  return (u16)r;
}
__device__ __forceinline__ float eluf(float z){
  return z > 0.f ? z : (__expf(z) - 1.f);
}
// flexible-dtype param load: f32 flag ? float : bf16
__device__ __forceinline__ float ldp(const void* p, int i, int f32f){
  return f32f ? ((const float*)p)[i] : bf2f(((const u16*)p)[i]);
}
// LDS byte-offset swizzle: rows stride 512B; XOR bits 4-6.
__device__ __forceinline__ int swz(int row, int cb){
  int m = ((row & 7) << 4) ^ ((row & 8) << 2);
  return (row << 9) + (cb ^ m);
}

// ---------------- dtype sniff: decide if inputs are f32 or bf16 ----------------
__global__ void k_sniff(const u16* __restrict__ x, int* __restrict__ flag){
  int t = threadIdx.x;
  u16 u = x[2*t];
  int e = (u >> 7) & 0xFF;
  int sane = (e >= 113 && e <= 134) ? 1 : 0;
  unsigned long long b = __ballot(sane);
  if (t == 0) *flag = (__popcll(b) < 32) ? 1 : 0;   // 1 = f32 inputs
}

// ---------------- weight transpose+canonicalize: W[k][n] -> WT[n][k] bf16 ----------------
__global__ void k_transpose(const int* __restrict__ flagp,
                            const void* __restrict__ W1, const void* __restrict__ W2,
                            const void* __restrict__ Wa, const void* __restrict__ Wo,
                            u16* __restrict__ W1T, u16* __restrict__ W2T,
                            u16* __restrict__ WaT, u16* __restrict__ WoT)
{
  const int f = *flagp;
  int idx = blockIdx.x * 256 + threadIdx.x;
  if (idx < 65536) {                       // W_in2hid 256x256
    int n = idx >> 8, k = idx & 255;
    W1T[idx] = f2bf(ldp(W1, k*256 + n, f));
  } else if (idx < 131072) {               // W_enc 256x256
    int j = idx - 65536;
    int n = j >> 8, k = j & 255;
    W2T[j] = f2bf(ldp(W2, k*256 + n, f));
  } else if (idx < 262144) {               // W_aggr 512x256 -> 256x512
    int j = idx - 131072;
    int n = j >> 9, k = j & 511;
    WaT[n*512 + k] = f2bf(ldp(Wa, k*256 + n, f));
  } else {                                 // W_out 256x64 -> 64x256
    int j = idx - 262144;
    int n = j >> 8, k = j & 255;
    WoT[n*256 + k] = f2bf(ldp(Wo, k*64 + n, f));
  }
}

// ---------------- virtual nodes (parallel rewrite) ----------------
// 256 threads; thread t owns output column t; 10 rows accumulate in 10
// independent registers (ILP); weight fragment loaded once per k-chunk.
__global__ void k_vnode(const int* __restrict__ flagp,
                        const void* __restrict__ embed, const u16* __restrict__ W1T,
                        const void* __restrict__ b1, const void* __restrict__ g1, const void* __restrict__ bb1,
                        const void* __restrict__ vbh,
                        const u16* __restrict__ W2T, const void* __restrict__ b2,
                        const void* __restrict__ vbd,
                        const u16* __restrict__ WaT, const void* __restrict__ ba,
                        float* __restrict__ vg)
{
  __shared__ float buf[PV][256];
  __shared__ float st[PV][2];
  const int f = *flagp;
  const int t = threadIdx.x;
  const int lane = t & 63;
  const int w = t >> 6;

  for (int r=0;r<PV;r++) buf[r][t] = ldp(embed, r*256 + t, f);
  __syncthreads();

  float acc[PV];

  // ---- layer 1: z = embed @ W1 + b1
  #pragma unroll
  for (int r=0;r<PV;r++) acc[r] = 0.f;
  for (int k8=0;k8<32;k8++){
    bf16x8 wv = *(const bf16x8*)(W1T + t*256 + k8*8);
    float wf[8];
    #pragma unroll
    for (int j=0;j<8;j++) wf[j] = bf2f((u16)wv[j]);
    #pragma unroll
    for (int r=0;r<PV;r++){
      f32x4 a0 = *(const f32x4*)(&buf[r][k8*8]);
      f32x4 a1 = *(const f32x4*)(&buf[r][k8*8+4]);
      acc[r] = fmaf(a0[0],wf[0],acc[r]); acc[r] = fmaf(a0[1],wf[1],acc[r]);
      acc[r] = fmaf(a0[2],wf[2],acc[r]); acc[r] = fmaf(a0[3],wf[3],acc[r]);
      acc[r] = fmaf(a1[0],wf[4],acc[r]); acc[r] = fmaf(a1[1],wf[5],acc[r]);
      acc[r] = fmaf(a1[2],wf[6],acc[r]); acc[r] = fmaf(a1[3],wf[7],acc[r]);
    }
  }
  {
    float bv = ldp(b1, t, f);
    #pragma unroll
    for (int r=0;r<PV;r++) acc[r] += bv;
  }
  __syncthreads();
  #pragma unroll
  for (int r=0;r<PV;r++) buf[r][t] = acc[r];
  __syncthreads();
  // LN stats: wave w handles rows w, w+4, w+8
  for (int r = w; r < PV; r += 4){
    float v0=buf[r][lane], v1=buf[r][lane+64], v2=buf[r][lane+128], v3=buf[r][lane+192];
    float s = v0+v1+v2+v3;
    float ss = v0*v0+v1*v1+v2*v2+v3*v3;
    #pragma unroll
    for (int off=1; off<64; off<<=1){ s += __shfl_xor(s,off,64); ss += __shfl_xor(ss,off,64); }
    if (lane==0){
      float mu = s*(1.f/256.f);
      float var = ss*(1.f/256.f) - mu*mu;
      st[r][0]=mu; st[r][1]=rsqrtf(var+1e-5f);
    }
  }
  __syncthreads();
  {
    float gv = ldp(g1,t,f), bbv = ldp(bb1,t,f);
    #pragma unroll
    for (int r=0;r<PV;r++){
      float v = (acc[r]-st[r][0])*st[r][1]*gv + bbv;
      buf[r][t] = eluf(v) + ldp(vbh, r*256+t, f);
    }
  }
  __syncthreads();

  // ---- layer 2: v_x = elu(h1 @ W2 + b2) + vbd
  #pragma unroll
  for (int r=0;r<PV;r++) acc[r] = 0.f;
  for (int k8=0;k8<32;k8++){
    bf16x8 wv = *(const bf16x8*)(W2T + t*256 + k8*8);
    float wf[8];
    #pragma unroll
    for (int j=0;j<8;j++) wf[j] = bf2f((u16)wv[j]);
    #pragma unroll
    for (int r=0;r<PV;r++){
      f32x4 a0 = *(const f32x4*)(&buf[r][k8*8]);
      f32x4 a1 = *(const f32x4*)(&buf[r][k8*8+4]);
      acc[r] = fmaf(a0[0],wf[0],acc[r]); acc[r] = fmaf(a0[1],wf[1],acc[r]);
      acc[r] = fmaf(a0[2],wf[2],acc[r]); acc[r] = fmaf(a0[3],wf[3],acc[r]);
      acc[r] = fmaf(a1[0],wf[4],acc[r]); acc[r] = fmaf(a1[1],wf[5],acc[r]);
      acc[r] = fmaf(a1[2],wf[6],acc[r]); acc[r] = fmaf(a1[3],wf[7],acc[r]);
    }
  }
  __syncthreads();
  {
    float bv = ldp(b2,t,f);
    #pragma unroll
    for (int r=0;r<PV;r++) buf[r][t] = eluf(acc[r]+bv) + ldp(vbd, r*256+t, f);
  }
  __syncthreads();

  // ---- layer 3: vg = v_x @ Wa_bottom + b_aggr
  #pragma unroll
  for (int r=0;r<PV;r++) acc[r] = 0.f;
  for (int k8=0;k8<32;k8++){
    bf16x8 wv = *(const bf16x8*)(WaT + t*512 + 256 + k8*8);
    float wf[8];
    #pragma unroll
    for (int j=0;j<8;j++) wf[j] = bf2f((u16)wv[j]);
    #pragma unroll
    for (int r=0;r<PV;r++){
      f32x4 a0 = *(const f32x4*)(&buf[r][k8*8]);
      f32x4 a1 = *(const f32x4*)(&buf[r][k8*8+4]);
      acc[r] = fmaf(a0[0],wf[0],acc[r]); acc[r] = fmaf(a0[1],wf[1],acc[r]);
      acc[r] = fmaf(a0[2],wf[2],acc[r]); acc[r] = fmaf(a0[3],wf[3],acc[r]);
      acc[r] = fmaf(a1[0],wf[4],acc[r]); acc[r] = fmaf(a1[1],wf[5],acc[r]);
      acc[r] = fmaf(a1[2],wf[6],acc[r]); acc[r] = fmaf(a1[3],wf[7],acc[r]);
    }
  }
  {
    float bv = ldp(ba,t,f);
    #pragma unroll
    for (int r=0;r<PV;r++) vg[r*256+t] = acc[r] + bv;
  }
}

// ---------------- cross-wave LayerNorm stats ----------------
__device__ __forceinline__ void ln_rows(f32x4 (&acc)[4][4], float2 (*part)[4], float2* stats,
                                        int tid, int wid, int q, int g)
{
  #pragma unroll
  for (int m=0;m<4;m++){
    #pragma unroll
    for (int j=0;j<4;j++){
      float s1=0.f, s2=0.f;
      #pragma unroll
      for (int n=0;n<4;n++){ float v = acc[m][n][j]; s1+=v; s2+=v*v; }
      s1 += __shfl_xor(s1,1,64); s2 += __shfl_xor(s2,1,64);
      s1 += __shfl_xor(s1,2,64); s2 += __shfl_xor(s2,2,64);
      s1 += __shfl_xor(s1,4,64); s2 += __shfl_xor(s2,4,64);
      s1 += __shfl_xor(s1,8,64); s2 += __shfl_xor(s2,8,64);
      if (q == 0) part[16*m + 4*g + j][wid] = make_float2(s1, s2);
    }
  }
  __syncthreads();
  if (tid < 64){
    float s=0.f, ss=0.f;
    #pragma unroll
    for (int w=0;w<4;w++){ float2 p = part[tid][w]; s+=p.x; ss+=p.y; }
    float mu = s*(1.f/256.f);
    float var = ss*(1.f/256.f) - mu*mu;
    stats[tid] = make_float2(mu, rsqrtf(var + 1e-5f));
  }
  __syncthreads();
}

// ---------------- main fused kernel ----------------
__global__ __launch_bounds__(256, 2) void k_main(
    const int* __restrict__ flagp,
    const void* __restrict__ x, const int* __restrict__ mapping,
    const void* __restrict__ b1, const void* __restrict__ g1, const void* __restrict__ bb1,
    const void* __restrict__ b2,
    const void* __restrict__ g3, const void* __restrict__ bb3,
    const void* __restrict__ bo,
    const u16* __restrict__ W1T, const u16* __restrict__ W2T,
    const u16* __restrict__ WaT, const u16* __restrict__ WoT,
    const float* __restrict__ vg, void* __restrict__ out)
{
  __shared__ __align__(16) u16 Abuf[64*256];
  __shared__ float2 part[64][4];
  __shared__ float2 stats[64];
  __shared__ int maplds[64];

  const int f = *flagp;
  const int tid = threadIdx.x;
  const int wid = tid >> 6;
  const int lane = tid & 63;
  const int q = lane & 15;
  const int g = lane >> 4;
  const int R0 = blockIdx.x * 64;

  // ---- stage x tile (64 x 256) into swizzled LDS as bf16 ----
  if (f) {
    const float* xr = (const float*)x + (size_t)R0 * 256;
    #pragma unroll
    for (int i=0;i<8;i++){
      int c = tid + 256*i;
      int row = c >> 5;
      int cb  = (c & 31) << 4;
      int e0  = (c & 31) << 3;
      float4 a = *(const float4*)(xr + row*256 + e0);
      float4 b = *(const float4*)(xr + row*256 + e0 + 4);
      union { u16 h[8]; i32x4 v; } pk;
      pk.h[0]=f2bf(a.x); pk.h[1]=f2bf(a.y); pk.h[2]=f2bf(a.z); pk.h[3]=f2bf(a.w);
      pk.h[4]=f2bf(b.x); pk.h[5]=f2bf(b.y); pk.h[6]=f2bf(b.z); pk.h[7]=f2bf(b.w);
      *(i32x4*)((char*)Abuf + swz(row, cb)) = pk.v;
    }
  } else {
    const u16* xr = (const u16*)x + (size_t)R0 * 256;
    #pragma unroll
    for (int i=0;i<8;i++){
      int c = tid + 256*i;
      int row = c >> 5;
      int cb  = (c & 31) << 4;
      i32x4 v = *(const i32x4*)(xr + row*256 + ((c&31)<<3));
      *(i32x4*)((char*)Abuf + swz(row, cb)) = v;
    }
  }
  if (tid < 64){
    int mv = mapping[R0 + tid];
    maplds[tid] = mv < 0 ? 0 : (mv > PV-1 ? PV-1 : mv);
  }
  __syncthreads();

  f32x4 acc[4][4];

  // ================= GEMM1: h1 = elu(LN(x @ W1 + b1)) =================
  {
    #pragma unroll
    for (int n=0;n<4;n++){
      float bv = ldp(b1, 64*wid + 16*n + q, f);
      #pragma unroll
      for (int m=0;m<4;m++) acc[m][n] = (f32x4){bv,bv,bv,bv};
    }
    #pragma unroll
    for (int s=0;s<8;s++){
      bf16x8 af[4], bw[4];
      #pragma unroll
      for (int m=0;m<4;m++) af[m] = *(const bf16x8*)((const char*)Abuf + swz(16*m+q, 64*s+16*g));
      #pragma unroll
      for (int n=0;n<4;n++) bw[n] = *(const bf16x8*)(W1T + (64*wid+16*n+q)*256 + 32*s + 8*g);
      #pragma unroll
      for (int m=0;m<4;m++){
        #pragma unroll
        for (int n=0;n<4;n++)
          acc[m][n] = __builtin_amdgcn_mfma_f32_16x16x32_bf16(af[m], bw[n], acc[m][n], 0,0,0);
      }
    }
  }
  ln_rows(acc, part, stats, tid, wid, q, g);
  {
    float gam[4], bet[4];
    #pragma unroll
    for (int n=0;n<4;n++){ int col = 64*wid+16*n+q; gam[n]=ldp(g1,col,f); bet[n]=ldp(bb1,col,f); }
    #pragma unroll
    for (int m=0;m<4;m++){
      #pragma unroll
      for (int j=0;j<4;j++){
        int row = 16*m + 4*g + j;
        float2 st = stats[row];
        #pragma unroll
        for (int n=0;n<4;n++){
          float v = (acc[m][n][j] - st.x) * st.y * gam[n] + bet[n];
          *(u16*)((char*)Abuf + swz(row, (64*wid+16*n+q)<<1)) = f2bf(eluf(v));
        }
      }
    }
  }
  __syncthreads();

  // ================= GEMM2: h2 = elu(h1 @ W2 + b2) =================
  {
    #pragma unroll
    for (int n=0;n<4;n++){
      float bv = ldp(b2, 64*wid + 16*n + q, f);
      #pragma unroll
      for (int m=0;m<4;m++) acc[m][n] = (f32x4){bv,bv,bv,bv};
    }
    #pragma unroll
    for (int s=0;s<8;s++){
      bf16x8 af[4], bw[4];
      #pragma unroll
      for (int m=0;m<4;m++) af[m] = *(const bf16x8*)((const char*)Abuf + swz(16*m+q, 64*s+16*g));
      #pragma unroll
      for (int n=0;n<4;n++) bw[n] = *(const bf16x8*)(W2T + (64*wid+16*n+q)*256 + 32*s + 8*g);
      #pragma unroll
      for (int m=0;m<4;m++){
        #pragma unroll
        for (int n=0;n<4;n++)
          acc[m][n] = __builtin_amdgcn_mfma_f32_16x16x32_bf16(af[m], bw[n], acc[m][n], 0,0,0);
      }
    }
  }
  __syncthreads();
  {
    #pragma unroll
    for (int m=0;m<4;m++){
      #pragma unroll
      for (int j=0;j<4;j++){
        int row = 16*m + 4*g + j;
        #pragma unroll
        for (int n=0;n<4;n++)
          *(u16*)((char*)Abuf + swz(row, (64*wid+16*n+q)<<1)) = f2bf(eluf(acc[m][n][j]));
      }
    }
  }
  __syncthreads();

  // ================= GEMM3: nx = elu(LN(h2 @ Wa_top + vg[map])) =================
  {
    #pragma unroll
    for (int m=0;m<4;m++){
      int mp[4];
      #pragma unroll
      for (int j=0;j<4;j++) mp[j] = maplds[16*m + 4*g + j];
      #pragma unroll
      for (int n=0;n<4;n++){
        int col = 64*wid + 16*n + q;
        #pragma unroll
        for (int j=0;j<4;j++) acc[m][n][j] = vg[mp[j]*256 + col];
      }
    }
    #pragma unroll
    for (int s=0;s<8;s++){
      bf16x8 af[4], bw[4];
      #pragma unroll
      for (int m=0;m<4;m++) af[m] = *(const bf16x8*)((const char*)Abuf + swz(16*m+q, 64*s+16*g));
      #pragma unroll
      for (int n=0;n<4;n++) bw[n] = *(const bf16x8*)(WaT + (64*wid+16*n+q)*512 + 32*s + 8*g);
      #pragma unroll
      for (int m=0;m<4;m++){
        #pragma unroll
        for (int n=0;n<4;n++)
          acc[m][n] = __builtin_amdgcn_mfma_f32_16x16x32_bf16(af[m], bw[n], acc[m][n], 0,0,0);
      }
    }
  }
  ln_rows(acc, part, stats, tid, wid, q, g);
  {
    float gam[4], bet[4];
    #pragma unroll
    for (int n=0;n<4;n++){ int col = 64*wid+16*n+q; gam[n]=ldp(g3,col,f); bet[n]=ldp(bb3,col,f); }
    #pragma unroll
    for (int m=0;m<4;m++){
      #pragma unroll
      for (int j=0;j<4;j++){
        int row = 16*m + 4*g + j;
        float2 st = stats[row];
        #pragma unroll
        for (int n=0;n<4;n++){
          float v = (acc[m][n][j] - st.x) * st.y * gam[n] + bet[n];
          *(u16*)((char*)Abuf + swz(row, (64*wid+16*n+q)<<1)) = f2bf(eluf(v));
        }
      }
    }
  }
  __syncthreads();

  // ================= GEMM4: out = nx @ Wout + bo =================
  {
    f32x4 a4[4];
    #pragma unroll
    for (int n=0;n<4;n++){ float bv = ldp(bo, 16*n+q, f); a4[n] = (f32x4){bv,bv,bv,bv}; }
    #pragma unroll
    for (int s=0;s<8;s++){
      bf16x8 af = *(const bf16x8*)((const char*)Abuf + swz(16*wid+q, 64*s+16*g));
      #pragma unroll
      for (int n=0;n<4;n++){
        bf16x8 bw = *(const bf16x8*)(WoT + (16*n+q)*256 + 32*s + 8*g);
        a4[n] = __builtin_amdgcn_mfma_f32_16x16x32_bf16(af, bw, a4[n], 0,0,0);
      }
    }
    if (f){
      float* outf = (float*)out;
      #pragma unroll
      for (int n=0;n<4;n++){
        #pragma unroll
        for (int j=0;j<4;j++){
          int grow = R0 + 16*wid + 4*g + j;
          outf[(size_t)grow*64 + 16*n + q] = a4[n][j];
        }
      }
    } else {
      u16* outh = (u16*)out;
      #pragma unroll
      for (int n=0;n<4;n++){
        #pragma unroll
        for (int j=0;j<4;j++){
          int grow = R0 + 16*wid + 4*g + j;
          outh[(size_t)grow*64 + 16*n + q] = f2bf(a4[n][j]);
        }
      }
    }
  }
}

extern "C" void kernel_launch(void* const* d_in, const int* in_sizes, int n_in,
                              void* d_out, int out_size, void* d_ws, size_t ws_size,
                              hipStream_t stream)
{
  const void* x    = d_in[0];
  const int* mapping = (const int*)d_in[1];
  const void* embed= d_in[2];
  const void* vbh  = d_in[3];
  const void* vbd  = d_in[4];
  const void* W1   = d_in[5];
  const void* b1   = d_in[6];
  const void* g1   = d_in[7];
  const void* bb1  = d_in[8];
  const void* W2   = d_in[9];
  const void* b2   = d_in[10];
  const void* g3   = d_in[11];
  const void* bb3  = d_in[12];
  const void* Wa   = d_in[13];
  const void* ba   = d_in[14];
  const void* Wo   = d_in[15];
  const void* bo   = d_in[16];

  char* ws = (char*)d_ws;
  int* flagp = (int*)ws;
  u16* W1T = (u16*)(ws + 64);
  u16* W2T = (u16*)(ws + 131136);
  u16* WaT = (u16*)(ws + 262208);
  u16* WoT = (u16*)(ws + 524352);
  float* vg = (float*)(ws + 557120);

  const int N = in_sizes[1];           // 200000, divisible by 64

  k_sniff<<<1, 64, 0, stream>>>((const u16*)x, flagp);
  k_transpose<<<1088, 256, 0, stream>>>(flagp, W1, W2, Wa, Wo, W1T, W2T, WaT, WoT);
  k_vnode<<<1, 256, 0, stream>>>(flagp, embed, W1T, b1, g1, bb1, vbh, W2T, b2, vbd, WaT, ba, vg);
  k_main<<<N/64, 256, 0, stream>>>(flagp, x, mapping, b1, g1, bb1, b2, g3, bb3, bo,
                                   W1T, W2T, WaT, WoT, vg, (void*)d_out);
}

// Round 5
// 309.121 us; speedup vs baseline: 2.5590x; 1.0621x over previous
//
#include <hip/hip_runtime.h>
#include <hip/hip_bf16.h>
#include <math.h>

typedef unsigned short u16;
typedef __attribute__((ext_vector_type(8))) short bf16x8;
typedef __attribute__((ext_vector_type(4))) float f32x4;
typedef __attribute__((ext_vector_type(4))) int i32x4;

#define PV 10

__device__ __forceinline__ float bf2f(u16 u){
  union{unsigned int i; float f;} v; v.i = ((unsigned int)u)<<16; return v.f;
}
__device__ __forceinline__ u16 f2bf(float f){
  union{float f; unsigned int i;} v; v.f = f;
  unsigned int r = (v.i + 0x7FFFu + ((v.i>>16)&1u))>>16;
  return (u16)r;
}
__device__ __forceinline__ float eluf(float z){
  return z > 0.f ? z : (__expf(z) - 1.f);
}
// flexible-dtype param load: f32 flag ? float : bf16
__device__ __forceinline__ float ldp(const void* p, int i, int f32f){
  return f32f ? ((const float*)p)[i] : bf2f(((const u16*)p)[i]);
}
// LDS byte-offset swizzle: rows stride 512B; XOR bits 4-6.
__device__ __forceinline__ int swz(int row, int cb){
  int m = ((row & 7) << 4) ^ ((row & 8) << 2);
  return (row << 9) + (cb ^ m);
}

// ---------------- dtype sniff: decide if inputs are f32 or bf16 ----------------
__global__ void k_sniff(const u16* __restrict__ x, int* __restrict__ flag){
  int t = threadIdx.x;
  u16 u = x[2*t];
  int e = (u >> 7) & 0xFF;
  int sane = (e >= 113 && e <= 134) ? 1 : 0;
  unsigned long long b = __ballot(sane);
  if (t == 0) *flag = (__popcll(b) < 32) ? 1 : 0;   // 1 = f32 inputs
}

// ---------------- weight pack into MFMA-fragment order ----------------
// element = w*16384 + s*2048 + n*512 + lane*8 + j  <=>
//   dst[(((w*8+s)*4+n)*64 + lane)*8 + j] = W[(32s+8g+j)*ldw + (64w+16n+q)]
// so the wave's 64 lanes read one contiguous 1KB block per (s,n).
__global__ void k_fragpack(const int* __restrict__ flagp,
                           const void* __restrict__ W1, const void* __restrict__ W2,
                           const void* __restrict__ Wa, const void* __restrict__ Wo,
                           u16* __restrict__ W1F, u16* __restrict__ W2F,
                           u16* __restrict__ WaF, u16* __restrict__ WoF)
{
  const int f = *flagp;
  int idx = blockIdx.x * 256 + threadIdx.x;
  if (idx < 196608) {                       // three 256x256 packs
    int local = idx & 65535;
    int which = idx >> 16;
    int j = local & 7;
    int fid = local >> 3;
    int lane = fid & 63, q = lane & 15, g = lane >> 4;
    int n = (fid >> 6) & 3;
    int s = (fid >> 8) & 7;
    int w = (fid >> 11) & 3;
    int col = 64*w + 16*n + q;
    int k = 32*s + 8*g + j;
    const void* src = which == 0 ? W1 : (which == 1 ? W2 : Wa);
    u16* dst = which == 0 ? W1F : (which == 1 ? W2F : WaF);
    dst[local] = f2bf(ldp(src, k*256 + col, f));   // Wa: top half (k<256)
  } else if (idx < 212992) {                // W_out 256x64
    int local = idx - 196608;
    int j = local & 7;
    int fid = local >> 3;
    int lane = fid & 63, q = lane & 15, g = lane >> 4;
    int n = (fid >> 6) & 3;
    int s = (fid >> 8) & 7;
    int col = 16*n + q;
    int k = 32*s + 8*g + j;
    WoF[local] = f2bf(ldp(Wo, k*64 + col, f));
  }
}

// ---------------- virtual nodes (reads raw weights, coalesced, 10-row ILP) ----------------
__global__ void k_vnode(const int* __restrict__ flagp,
                        const void* __restrict__ embed, const void* __restrict__ W1,
                        const void* __restrict__ b1, const void* __restrict__ g1, const void* __restrict__ bb1,
                        const void* __restrict__ vbh,
                        const void* __restrict__ W2, const void* __restrict__ b2,
                        const void* __restrict__ vbd,
                        const void* __restrict__ Wa, const void* __restrict__ ba,
                        float* __restrict__ vg)
{
  __shared__ float buf[PV][256];
  __shared__ float st[PV][2];
  const int f = *flagp;
  const int t = threadIdx.x;
  const int lane = t & 63;
  const int w = t >> 6;

  for (int r=0;r<PV;r++) buf[r][t] = ldp(embed, r*256 + t, f);
  __syncthreads();

  float acc[PV];

  // ---- layer 1: z = embed @ W1 + b1   (thread t = col t; W1[k][t] reads coalesced)
  #pragma unroll
  for (int r=0;r<PV;r++) acc[r] = 0.f;
  for (int k8=0;k8<32;k8++){
    float wf[8];
    #pragma unroll
    for (int j=0;j<8;j++) wf[j] = ldp(W1, (k8*8+j)*256 + t, f);
    #pragma unroll
    for (int r=0;r<PV;r++){
      f32x4 a0 = *(const f32x4*)(&buf[r][k8*8]);
      f32x4 a1 = *(const f32x4*)(&buf[r][k8*8+4]);
      acc[r] = fmaf(a0[0],wf[0],acc[r]); acc[r] = fmaf(a0[1],wf[1],acc[r]);
      acc[r] = fmaf(a0[2],wf[2],acc[r]); acc[r] = fmaf(a0[3],wf[3],acc[r]);
      acc[r] = fmaf(a1[0],wf[4],acc[r]); acc[r] = fmaf(a1[1],wf[5],acc[r]);
      acc[r] = fmaf(a1[2],wf[6],acc[r]); acc[r] = fmaf(a1[3],wf[7],acc[r]);
    }
  }
  {
    float bv = ldp(b1, t, f);
    #pragma unroll
    for (int r=0;r<PV;r++) acc[r] += bv;
  }
  __syncthreads();
  #pragma unroll
  for (int r=0;r<PV;r++) buf[r][t] = acc[r];
  __syncthreads();
  for (int r = w; r < PV; r += 4){
    float v0=buf[r][lane], v1=buf[r][lane+64], v2=buf[r][lane+128], v3=buf[r][lane+192];
    float s = v0+v1+v2+v3;
    float ss = v0*v0+v1*v1+v2*v2+v3*v3;
    #pragma unroll
    for (int off=1; off<64; off<<=1){ s += __shfl_xor(s,off,64); ss += __shfl_xor(ss,off,64); }
    if (lane==0){
      float mu = s*(1.f/256.f);
      float var = ss*(1.f/256.f) - mu*mu;
      st[r][0]=mu; st[r][1]=rsqrtf(var+1e-5f);
    }
  }
  __syncthreads();
  {
    float gv = ldp(g1,t,f), bbv = ldp(bb1,t,f);
    #pragma unroll
    for (int r=0;r<PV;r++){
      float v = (acc[r]-st[r][0])*st[r][1]*gv + bbv;
      buf[r][t] = eluf(v) + ldp(vbh, r*256+t, f);
    }
  }
  __syncthreads();

  // ---- layer 2: v_x = elu(h1 @ W2 + b2) + vbd
  #pragma unroll
  for (int r=0;r<PV;r++) acc[r] = 0.f;
  for (int k8=0;k8<32;k8++){
    float wf[8];
    #pragma unroll
    for (int j=0;j<8;j++) wf[j] = ldp(W2, (k8*8+j)*256 + t, f);
    #pragma unroll
    for (int r=0;r<PV;r++){
      f32x4 a0 = *(const f32x4*)(&buf[r][k8*8]);
      f32x4 a1 = *(const f32x4*)(&buf[r][k8*8+4]);
      acc[r] = fmaf(a0[0],wf[0],acc[r]); acc[r] = fmaf(a0[1],wf[1],acc[r]);
      acc[r] = fmaf(a0[2],wf[2],acc[r]); acc[r] = fmaf(a0[3],wf[3],acc[r]);
      acc[r] = fmaf(a1[0],wf[4],acc[r]); acc[r] = fmaf(a1[1],wf[5],acc[r]);
      acc[r] = fmaf(a1[2],wf[6],acc[r]); acc[r] = fmaf(a1[3],wf[7],acc[r]);
    }
  }
  __syncthreads();
  {
    float bv = ldp(b2,t,f);
    #pragma unroll
    for (int r=0;r<PV;r++) buf[r][t] = eluf(acc[r]+bv) + ldp(vbd, r*256+t, f);
  }
  __syncthreads();

  // ---- layer 3: vg = v_x @ Wa_bottom + b_aggr   (Wa rows 256..511)
  #pragma unroll
  for (int r=0;r<PV;r++) acc[r] = 0.f;
  for (int k8=0;k8<32;k8++){
    float wf[8];
    #pragma unroll
    for (int j=0;j<8;j++) wf[j] = ldp(Wa, (256 + k8*8+j)*256 + t, f);
    #pragma unroll
    for (int r=0;r<PV;r++){
      f32x4 a0 = *(const f32x4*)(&buf[r][k8*8]);
      f32x4 a1 = *(const f32x4*)(&buf[r][k8*8+4]);
      acc[r] = fmaf(a0[0],wf[0],acc[r]); acc[r] = fmaf(a0[1],wf[1],acc[r]);
      acc[r] = fmaf(a0[2],wf[2],acc[r]); acc[r] = fmaf(a0[3],wf[3],acc[r]);
      acc[r] = fmaf(a1[0],wf[4],acc[r]); acc[r] = fmaf(a1[1],wf[5],acc[r]);
      acc[r] = fmaf(a1[2],wf[6],acc[r]); acc[r] = fmaf(a1[3],wf[7],acc[r]);
    }
  }
  {
    float bv = ldp(ba,t,f);
    #pragma unroll
    for (int r=0;r<PV;r++) vg[r*256+t] = acc[r] + bv;
  }
}

// ---------------- cross-wave LayerNorm stats ----------------
__device__ __forceinline__ void ln_rows(f32x4 (&acc)[4][4], float2 (*part)[4], float2* stats,
                                        int tid, int wid, int q, int g)
{
  #pragma unroll
  for (int m=0;m<4;m++){
    #pragma unroll
    for (int j=0;j<4;j++){
      float s1=0.f, s2=0.f;
      #pragma unroll
      for (int n=0;n<4;n++){ float v = acc[m][n][j]; s1+=v; s2+=v*v; }
      s1 += __shfl_xor(s1,1,64); s2 += __shfl_xor(s2,1,64);
      s1 += __shfl_xor(s1,2,64); s2 += __shfl_xor(s2,2,64);
      s1 += __shfl_xor(s1,4,64); s2 += __shfl_xor(s2,4,64);
      s1 += __shfl_xor(s1,8,64); s2 += __shfl_xor(s2,8,64);
      if (q == 0) part[16*m + 4*g + j][wid] = make_float2(s1, s2);
    }
  }
  __syncthreads();
  if (tid < 64){
    float s=0.f, ss=0.f;
    #pragma unroll
    for (int w=0;w<4;w++){ float2 p = part[tid][w]; s+=p.x; ss+=p.y; }
    float mu = s*(1.f/256.f);
    float var = ss*(1.f/256.f) - mu*mu;
    stats[tid] = make_float2(mu, rsqrtf(var + 1e-5f));
  }
  __syncthreads();
}

// ---------------- main fused kernel ----------------
__global__ __launch_bounds__(256, 2) void k_main(
    const int* __restrict__ flagp,
    const void* __restrict__ x, const int* __restrict__ mapping,
    const void* __restrict__ b1, const void* __restrict__ g1, const void* __restrict__ bb1,
    const void* __restrict__ b2,
    const void* __restrict__ g3, const void* __restrict__ bb3,
    const void* __restrict__ bo,
    const u16* __restrict__ W1F, const u16* __restrict__ W2F,
    const u16* __restrict__ WaF, const u16* __restrict__ WoF,
    const float* __restrict__ vg, void* __restrict__ out)
{
  __shared__ __align__(16) u16 Abuf[64*256];
  __shared__ float2 part[64][4];
  __shared__ float2 stats[64];
  __shared__ int maplds[64];

  const int f = *flagp;
  const int tid = threadIdx.x;
  const int wid = tid >> 6;
  const int lane = tid & 63;
  const int q = lane & 15;
  const int g = lane >> 4;
  const int R0 = blockIdx.x * 64;

  // ---- stage x tile (64 x 256) into swizzled LDS as bf16 ----
  if (f) {
    const float* xr = (const float*)x + (size_t)R0 * 256;
    #pragma unroll
    for (int i=0;i<8;i++){
      int c = tid + 256*i;
      int row = c >> 5;
      int cb  = (c & 31) << 4;
      int e0  = (c & 31) << 3;
      float4 a = *(const float4*)(xr + row*256 + e0);
      float4 b = *(const float4*)(xr + row*256 + e0 + 4);
      union { u16 h[8]; i32x4 v; } pk;
      pk.h[0]=f2bf(a.x); pk.h[1]=f2bf(a.y); pk.h[2]=f2bf(a.z); pk.h[3]=f2bf(a.w);
      pk.h[4]=f2bf(b.x); pk.h[5]=f2bf(b.y); pk.h[6]=f2bf(b.z); pk.h[7]=f2bf(b.w);
      *(i32x4*)((char*)Abuf + swz(row, cb)) = pk.v;
    }
  } else {
    const u16* xr = (const u16*)x + (size_t)R0 * 256;
    #pragma unroll
    for (int i=0;i<8;i++){
      int c = tid + 256*i;
      int row = c >> 5;
      int cb  = (c & 31) << 4;
      i32x4 v = *(const i32x4*)(xr + row*256 + ((c&31)<<3));
      *(i32x4*)((char*)Abuf + swz(row, cb)) = v;
    }
  }
  if (tid < 64){
    int mv = mapping[R0 + tid];
    maplds[tid] = mv < 0 ? 0 : (mv > PV-1 ? PV-1 : mv);
  }
  __syncthreads();

  f32x4 acc[4][4];
  const int fbase = wid*16384 + lane*8;   // w-stride = 8*4*64*8 = 16384 u16

  // ================= GEMM1: h1 = elu(LN(x @ W1 + b1)) =================
  {
    #pragma unroll
    for (int n=0;n<4;n++){
      float bv = ldp(b1, 64*wid + 16*n + q, f);
      #pragma unroll
      for (int m=0;m<4;m++) acc[m][n] = (f32x4){bv,bv,bv,bv};
    }
    #pragma unroll
    for (int s=0;s<8;s++){
      bf16x8 af[4], bw[4];
      #pragma unroll
      for (int m=0;m<4;m++) af[m] = *(const bf16x8*)((const char*)Abuf + swz(16*m+q, 64*s+16*g));
      #pragma unroll
      for (int n=0;n<4;n++) bw[n] = *(const bf16x8*)(W1F + fbase + (s*4+n)*512);
      #pragma unroll
      for (int m=0;m<4;m++){
        #pragma unroll
        for (int n=0;n<4;n++)
          acc[m][n] = __builtin_amdgcn_mfma_f32_16x16x32_bf16(af[m], bw[n], acc[m][n], 0,0,0);
      }
    }
  }
  ln_rows(acc, part, stats, tid, wid, q, g);
  {
    float gam[4], bet[4];
    #pragma unroll
    for (int n=0;n<4;n++){ int col = 64*wid+16*n+q; gam[n]=ldp(g1,col,f); bet[n]=ldp(bb1,col,f); }
    #pragma unroll
    for (int m=0;m<4;m++){
      #pragma unroll
      for (int j=0;j<4;j++){
        int row = 16*m + 4*g + j;
        float2 st = stats[row];
        #pragma unroll
        for (int n=0;n<4;n++){
          float v = (acc[m][n][j] - st.x) * st.y * gam[n] + bet[n];
          *(u16*)((char*)Abuf + swz(row, (64*wid+16*n+q)<<1)) = f2bf(eluf(v));
        }
      }
    }
  }
  __syncthreads();

  // ================= GEMM2: h2 = elu(h1 @ W2 + b2) =================
  {
    #pragma unroll
    for (int n=0;n<4;n++){
      float bv = ldp(b2, 64*wid + 16*n + q, f);
      #pragma unroll
      for (int m=0;m<4;m++) acc[m][n] = (f32x4){bv,bv,bv,bv};
    }
    #pragma unroll
    for (int s=0;s<8;s++){
      bf16x8 af[4], bw[4];
      #pragma unroll
      for (int m=0;m<4;m++) af[m] = *(const bf16x8*)((const char*)Abuf + swz(16*m+q, 64*s+16*g));
      #pragma unroll
      for (int n=0;n<4;n++) bw[n] = *(const bf16x8*)(W2F + fbase + (s*4+n)*512);
      #pragma unroll
      for (int m=0;m<4;m++){
        #pragma unroll
        for (int n=0;n<4;n++)
          acc[m][n] = __builtin_amdgcn_mfma_f32_16x16x32_bf16(af[m], bw[n], acc[m][n], 0,0,0);
      }
    }
  }
  __syncthreads();
  {
    #pragma unroll
    for (int m=0;m<4;m++){
      #pragma unroll
      for (int j=0;j<4;j++){
        int row = 16*m + 4*g + j;
        #pragma unroll
        for (int n=0;n<4;n++)
          *(u16*)((char*)Abuf + swz(row, (64*wid+16*n+q)<<1)) = f2bf(eluf(acc[m][n][j]));
      }
    }
  }
  __syncthreads();

  // ================= GEMM3: nx = elu(LN(h2 @ Wa_top + vg[map])) =================
  {
    #pragma unroll
    for (int m=0;m<4;m++){
      int mp[4];
      #pragma unroll
      for (int j=0;j<4;j++) mp[j] = maplds[16*m + 4*g + j];
      #pragma unroll
      for (int n=0;n<4;n++){
        int col = 64*wid + 16*n + q;
        #pragma unroll
        for (int j=0;j<4;j++) acc[m][n][j] = vg[mp[j]*256 + col];
      }
    }
    #pragma unroll
    for (int s=0;s<8;s++){
      bf16x8 af[4], bw[4];
      #pragma unroll
      for (int m=0;m<4;m++) af[m] = *(const bf16x8*)((const char*)Abuf + swz(16*m+q, 64*s+16*g));
      #pragma unroll
      for (int n=0;n<4;n++) bw[n] = *(const bf16x8*)(WaF + fbase + (s*4+n)*512);
      #pragma unroll
      for (int m=0;m<4;m++){
        #pragma unroll
        for (int n=0;n<4;n++)
          acc[m][n] = __builtin_amdgcn_mfma_f32_16x16x32_bf16(af[m], bw[n], acc[m][n], 0,0,0);
      }
    }
  }
  ln_rows(acc, part, stats, tid, wid, q, g);
  {
    float gam[4], bet[4];
    #pragma unroll
    for (int n=0;n<4;n++){ int col = 64*wid+16*n+q; gam[n]=ldp(g3,col,f); bet[n]=ldp(bb3,col,f); }
    #pragma unroll
    for (int m=0;m<4;m++){
      #pragma unroll
      for (int j=0;j<4;j++){
        int row = 16*m + 4*g + j;
        float2 st = stats[row];
        #pragma unroll
        for (int n=0;n<4;n++){
          float v = (acc[m][n][j] - st.x) * st.y * gam[n] + bet[n];
          *(u16*)((char*)Abuf + swz(row, (64*wid+16*n+q)<<1)) = f2bf(eluf(v));
        }
      }
    }
  }
  __syncthreads();

  // ================= GEMM4: out = nx @ Wout + bo =================
  {
    f32x4 a4[4];
    #pragma unroll
    for (int n=0;n<4;n++){ float bv = ldp(bo, 16*n+q, f); a4[n] = (f32x4){bv,bv,bv,bv}; }
    #pragma unroll
    for (int s=0;s<8;s++){
      bf16x8 af = *(const bf16x8*)((const char*)Abuf + swz(16*wid+q, 64*s+16*g));
      #pragma unroll
      for (int n=0;n<4;n++){
        bf16x8 bw = *(const bf16x8*)(WoF + (s*4+n)*512 + lane*8);
        a4[n] = __builtin_amdgcn_mfma_f32_16x16x32_bf16(af, bw, a4[n], 0,0,0);
      }
    }
    if (f){
      float* outf = (float*)out;
      #pragma unroll
      for (int n=0;n<4;n++){
        #pragma unroll
        for (int j=0;j<4;j++){
          int grow = R0 + 16*wid + 4*g + j;
          outf[(size_t)grow*64 + 16*n + q] = a4[n][j];
        }
      }
    } else {
      u16* outh = (u16*)out;
      #pragma unroll
      for (int n=0;n<4;n++){
        #pragma unroll
        for (int j=0;j<4;j++){
          int grow = R0 + 16*wid + 4*g + j;
          outh[(size_t)grow*64 + 16*n + q] = f2bf(a4[n][j]);
        }
      }
    }
  }
}

extern "C" void kernel_launch(void* const* d_in, const int* in_sizes, int n_in,
                              void* d_out, int out_size, void* d_ws, size_t ws_size,
                              hipStream_t stream)
{
  const void* x    = d_in[0];
  const int* mapping = (const int*)d_in[1];
  const void* embed= d_in[2];
  const void* vbh  = d_in[3];
  const void* vbd  = d_in[4];
  const void* W1   = d_in[5];
  const void* b1   = d_in[6];
  const void* g1   = d_in[7];
  const void* bb1  = d_in[8];
  const void* W2   = d_in[9];
  const void* b2   = d_in[10];
  const void* g3   = d_in[11];
  const void* bb3  = d_in[12];
  const void* Wa   = d_in[13];
  const void* ba   = d_in[14];
  const void* Wo   = d_in[15];
  const void* bo   = d_in[16];

  char* ws = (char*)d_ws;
  int* flagp = (int*)ws;
  u16* W1F = (u16*)(ws + 4096);
  u16* W2F = (u16*)(ws + 4096 + 131072);
  u16* WaF = (u16*)(ws + 4096 + 262144);
  u16* WoF = (u16*)(ws + 4096 + 393216);
  float* vg = (float*)(ws + 4096 + 425984);

  const int N = in_sizes[1];           // 200000, divisible by 64

  k_sniff<<<1, 64, 0, stream>>>((const u16*)x, flagp);
  k_fragpack<<<832, 256, 0, stream>>>(flagp, W1, W2, Wa, Wo, W1F, W2F, WaF, WoF);
  k_vnode<<<1, 256, 0, stream>>>(flagp, embed, W1, b1, g1, bb1, vbh, W2, b2, vbd, Wa, ba, vg);
  k_main<<<N/64, 256, 0, stream>>>(flagp, x, mapping, b1, g1, bb1, b2, g3, bb3, bo,
                                   W1F, W2F, WaF, WoF, vg, (void*)d_out);
}